// Round 7
// baseline (128.214 us; speedup 1.0000x reference)
//
#include <hip/hip_runtime.h>
#include <stdint.h>

// Problem constants (B, L, D, H) = (8, 256, 512, 512)
#define Bb 8
#define Ll 256
#define Dd 512
#define Hh 512
#define Nout (Ll * Bb * Ll)   // 524288 elements per output tensor
#define HALFSZ ((size_t)Bb * Ll * Hh)  // elements in one K-half partial (1M)

#define Kc 2.8853900817779268  // 2/ln(2):  exp2(Kc*s) = e^(2s)

// JAX threefry mode: 1 = partitionable (default since jax 0.4.30)
#define RNG_PARTITIONABLE 1

typedef __attribute__((ext_vector_type(8))) short bf16x8;   // 4 VGPRs
typedef __attribute__((ext_vector_type(4))) float f32x4;    // MFMA C/D

// ---------------------------------------------------------------------------
// Threefry2x32 with key = (0, 42)  (jax.random.key(42))
// ---------------------------------------------------------------------------
__device__ __forceinline__ uint32_t rotl32(uint32_t v, int s) {
  return (v << s) | (v >> (32 - s));
}
__device__ __forceinline__ void tf_round(uint32_t& x0, uint32_t& x1, int r) {
  x0 += x1;
  x1 = rotl32(x1, r);
  x1 ^= x0;
}
__device__ __forceinline__ uint2 threefry2x32_k042(uint32_t x0, uint32_t x1) {
  const uint32_t k0 = 0u;
  const uint32_t k1 = 42u;
  const uint32_t k2 = 0x1BD11BDAu ^ k0 ^ k1;
  x0 += k0; x1 += k1;
  tf_round(x0, x1, 13); tf_round(x0, x1, 15); tf_round(x0, x1, 26); tf_round(x0, x1, 6);
  x0 += k1; x1 += k2 + 1u;
  tf_round(x0, x1, 17); tf_round(x0, x1, 29); tf_round(x0, x1, 16); tf_round(x0, x1, 24);
  x0 += k2; x1 += k0 + 2u;
  tf_round(x0, x1, 13); tf_round(x0, x1, 15); tf_round(x0, x1, 26); tf_round(x0, x1, 6);
  x0 += k0; x1 += k1 + 3u;
  tf_round(x0, x1, 17); tf_round(x0, x1, 29); tf_round(x0, x1, 16); tf_round(x0, x1, 24);
  x0 += k1; x1 += k2 + 4u;
  tf_round(x0, x1, 13); tf_round(x0, x1, 15); tf_round(x0, x1, 26); tf_round(x0, x1, 6);
  x0 += k2; x1 += k0 + 5u;
  return make_uint2(x0, x1);
}

__device__ __forceinline__ uint32_t rng_bits(uint32_t n) {
#if RNG_PARTITIONABLE
  uint2 o = threefry2x32_k042(0u, n);
  return o.x ^ o.y;
#else
  const uint32_t half = (uint32_t)(Nout / 2);
  if (n < half) {
    uint2 o = threefry2x32_k042(n, n + half);
    return o.x;
  } else {
    uint2 o = threefry2x32_k042(n - half, n);
    return o.y;
  }
#endif
}

// ---------------------------------------------------------------------------
// bf16 helpers (round-to-nearest-even split; residuals are exact in fp32)
// ---------------------------------------------------------------------------
__device__ __forceinline__ unsigned short bf16_rne(float f) {
  uint32_t u = __float_as_uint(f);
  u = (u + 0x7fffu + ((u >> 16) & 1u)) >> 16;
  return (unsigned short)u;
}
__device__ __forceinline__ float bf16_tof(unsigned short h) {
  return __uint_as_float(((uint32_t)h) << 16);
}
__device__ __forceinline__ void split3(float a, unsigned short& h,
                                       unsigned short& m, unsigned short& l) {
  h = bf16_rne(a);
  const float r1 = a - bf16_tof(h);
  m = bf16_rne(r1);
  const float r2 = r1 - bf16_tof(m);
  l = bf16_rne(r2);
}

// ---------------------------------------------------------------------------
// Pre-pass 1: split enc (fp32 [2048][512]) into 3 bf16 planes, same layout.
// ---------------------------------------------------------------------------
__global__ __launch_bounds__(256) void split_enc(
    const float* __restrict__ enc, unsigned short* __restrict__ ah,
    unsigned short* __restrict__ am, unsigned short* __restrict__ al) {
  const int idx = (blockIdx.x * 256 + threadIdx.x) * 4;
  const float4 v = *(const float4*)(enc + idx);
  ushort4 h4, m4, l4;
  split3(v.x, h4.x, m4.x, l4.x);
  split3(v.y, h4.y, m4.y, l4.y);
  split3(v.z, h4.z, m4.z, l4.z);
  split3(v.w, h4.w, m4.w, l4.w);
  *(ushort4*)(ah + idx) = h4;
  *(ushort4*)(am + idx) = m4;
  *(ushort4*)(al + idx) = l4;
}

// ---------------------------------------------------------------------------
// Pre-pass 2: Wt[n][k] = W[k][n], split into 3 bf16 planes. 64x64 LDS tile.
// z = 0 -> W_l, z = 1 -> W_r; outputs offset by z*512*512.
// ---------------------------------------------------------------------------
__global__ __launch_bounds__(256) void split_wt(
    const float* __restrict__ Wl, const float* __restrict__ Wr,
    unsigned short* __restrict__ wh, unsigned short* __restrict__ wm,
    unsigned short* __restrict__ wl) {
  const int z = blockIdx.z;
  const float* W = z ? Wr : Wl;
  const size_t zo = (size_t)z * Hh * Dd;
  const int k0 = blockIdx.x * 64;
  const int n0 = blockIdx.y * 64;
  __shared__ float tile[64][65];

  const int t = threadIdx.x;
#pragma unroll
  for (int rep = 0; rep < 4; ++rep) {
    const int idx = t + rep * 256;
    const int r = idx >> 4;         // k within tile
    const int c = (idx & 15) * 4;   // n within tile
    const float4 v = *(const float4*)(W + (size_t)(k0 + r) * Hh + n0 + c);
    tile[r][c + 0] = v.x; tile[r][c + 1] = v.y;
    tile[r][c + 2] = v.z; tile[r][c + 3] = v.w;
  }
  __syncthreads();
#pragma unroll
  for (int rep = 0; rep < 4; ++rep) {
    const int idx = t + rep * 256;
    const int rr = idx >> 4;        // n within tile
    const int cc = (idx & 15) * 4;  // k within tile
    ushort4 h4, m4, l4;
    split3(tile[cc + 0][rr], h4.x, m4.x, l4.x);
    split3(tile[cc + 1][rr], h4.y, m4.y, l4.y);
    split3(tile[cc + 2][rr], h4.z, m4.z, l4.z);
    split3(tile[cc + 3][rr], h4.w, m4.w, l4.w);
    const size_t o = zo + (size_t)(n0 + rr) * Dd + k0 + cc;
    *(ushort4*)(wh + o) = h4;
    *(ushort4*)(wm + o) = m4;
    *(ushort4*)(wl + o) = l4;
  }
}

// ---------------------------------------------------------------------------
// Kernel 1: K-SPLIT x2 GEMM partials.  elp/erp[half] = acc_half (raw fp32),
// where acc_half is EXACTLY the former acc[hf] MFMA sequence (kc 0..7 of the
// given K-half, same 6-MFMA order) — bit-identical partials. The former
// epilogue (double add + exp2) moves verbatim into biaffine_part staging.
//
// Why: R5 pinned gemm at ~24.7 us; R6 showed in-chain scheduling is neutral.
// The bottleneck model is now parallelism: 512 blocks = 2 blocks/CU
// (grid-limited) x 16-step serial K-chain. This kernel: 1024 blocks,
// 48 KB LDS -> 3 blocks/CU, 8-step chain, same total staging traffic.
// Counted-vmcnt depth-1 prefetch retained (never drain in steady state).
// ---------------------------------------------------------------------------
__global__ __launch_bounds__(256) void gemm_mfma(
    const unsigned short* __restrict__ ah, const unsigned short* __restrict__ am,
    const unsigned short* __restrict__ al, const unsigned short* __restrict__ wh,
    const unsigned short* __restrict__ wm, const unsigned short* __restrict__ wl,
    float* __restrict__ elp, float* __restrict__ erp) {
  const int flat = blockIdx.x;        // 0..1023
  const int xcd = flat & 7;
  const int half = (flat >> 3) & 1;   // K-half: kc global 0..7 or 8..15
  const int loc = flat >> 4;          // 0..63
  const int z = loc >> 5;             // 0..1
  const int ni = (loc >> 2) & 7;      // 0..7
  const int mi = (xcd << 2) | (loc & 3);  // 0..31
  const size_t zo = (size_t)z * Hh * Dd;
  float* C = (z ? erp : elp) + (size_t)half * HALFSZ;
  const int m0 = mi * 64;
  const int n0 = ni * 64;
  const int kh0 = half * 256;         // element offset of this K-half

  // [buf=2][12 blocks of 512 u16 = 1KB] -> 48 KB total (3 blocks/CU)
  __shared__ unsigned short Asm[2][12 * 512];
  __shared__ unsigned short Bsm[2][12 * 512];

  const int t = threadIdx.x;
  const int lane = t & 63;
  const int wv = t >> 6;
  const int l15 = lane & 15;
  const int kq8 = (lane >> 4) * 8;

  // staging descriptors: 6 loads per wave, q = wv*6 + s in 0..23
  const unsigned short* gp[6];
  size_t go[6];      // element offset, without k0
  int lq[6];         // LDS block index (u16 units, without buf)
  bool isA[6];
#pragma unroll
  for (int s = 0; s < 6; ++s) {
    const int q = wv * 6 + s;
    if (q < 12) {
      const int p = q >> 2, mt = q & 3;
      gp[s] = (p == 0) ? ah : (p == 1) ? am : al;
      go[s] = (size_t)(m0 + mt * 16 + l15) * Dd + kq8;
      lq[s] = q * 512;
      isA[s] = true;
    } else {
      const int q2 = q - 12;
      const int p = q2 >> 2, nt = q2 & 3;
      gp[s] = (p == 0) ? wh : (p == 1) ? wm : wl;
      go[s] = zo + (size_t)(n0 + nt * 16 + l15) * Dd + kq8;
      lq[s] = q2 * 512;
      isA[s] = false;
    }
  }

  auto stage = [&](int buf, int kc) {
    const int k0 = kh0 + kc * 32;
#pragma unroll
    for (int s = 0; s < 6; ++s) {
      unsigned short* dst = isA[s] ? &Asm[buf][lq[s]] : &Bsm[buf][lq[s]];
      __builtin_amdgcn_global_load_lds(
          (const __attribute__((address_space(1))) void*)(gp[s] + go[s] + k0),
          (__attribute__((address_space(3))) void*)dst, 16, 0, 0);
    }
  };

  const int mp = wv & 1;   // m-pair: mtiles {2mp, 2mp+1}
  const int np = wv >> 1;  // n-pair: ntiles {2np, 2np+1}

  f32x4 acc[2][2];  // [mi2][ni2] — single K-half accumulator
#pragma unroll
  for (int mi2 = 0; mi2 < 2; ++mi2)
#pragma unroll
    for (int ni2 = 0; ni2 < 2; ++ni2) acc[mi2][ni2] = (f32x4){0.f, 0.f, 0.f, 0.f};

  stage(0, 0);

#pragma unroll
  for (int kc = 0; kc < 8; ++kc) {
    const int buf = kc & 1;
    if (kc < 7) stage(buf ^ 1, kc + 1);

    // counted wait: newest 6 loads (stage kc+1) stay in flight; stage kc
    // has landed. Tail (kc==7): nothing newer, drain.
    if (kc < 7) {
      asm volatile("s_waitcnt vmcnt(6)" ::: "memory");
    } else {
      asm volatile("s_waitcnt vmcnt(0)" ::: "memory");
    }
    __builtin_amdgcn_s_barrier();
    __builtin_amdgcn_sched_barrier(0);

    bf16x8 af[2][3], bfr[2][3];
#pragma unroll
    for (int mi2 = 0; mi2 < 2; ++mi2)
#pragma unroll
      for (int p = 0; p < 3; ++p)
        af[mi2][p] = *(const bf16x8*)&Asm[buf][(p * 4 + mp * 2 + mi2) * 512 + lane * 8];
#pragma unroll
    for (int ni2 = 0; ni2 < 2; ++ni2)
#pragma unroll
      for (int p = 0; p < 3; ++p)
        bfr[ni2][p] = *(const bf16x8*)&Bsm[buf][(p * 4 + np * 2 + ni2) * 512 + lane * 8];

#pragma unroll
    for (int mi2 = 0; mi2 < 2; ++mi2)
#pragma unroll
      for (int ni2 = 0; ni2 < 2; ++ni2) {
        f32x4 A = acc[mi2][ni2];
        A = __builtin_amdgcn_mfma_f32_16x16x32_bf16(af[mi2][0], bfr[ni2][0], A, 0, 0, 0);
        A = __builtin_amdgcn_mfma_f32_16x16x32_bf16(af[mi2][0], bfr[ni2][1], A, 0, 0, 0);
        A = __builtin_amdgcn_mfma_f32_16x16x32_bf16(af[mi2][1], bfr[ni2][0], A, 0, 0, 0);
        A = __builtin_amdgcn_mfma_f32_16x16x32_bf16(af[mi2][0], bfr[ni2][2], A, 0, 0, 0);
        A = __builtin_amdgcn_mfma_f32_16x16x32_bf16(af[mi2][2], bfr[ni2][0], A, 0, 0, 0);
        A = __builtin_amdgcn_mfma_f32_16x16x32_bf16(af[mi2][1], bfr[ni2][1], A, 0, 0, 0);
        acc[mi2][ni2] = A;
      }

    // pin this wave's ds_reads of buf before the barrier so next iter's
    // stage into buf cannot race a lagging reader (rule #18 discipline).
    asm volatile("s_waitcnt lgkmcnt(0)" ::: "memory");
    __builtin_amdgcn_sched_barrier(0);
    __builtin_amdgcn_s_barrier();
  }

  const int rbase = (lane >> 4) * 4;
#pragma unroll
  for (int mi2 = 0; mi2 < 2; ++mi2) {
    const int mbase = m0 + (mp * 2 + mi2) * 16 + rbase;
#pragma unroll
    for (int ni2 = 0; ni2 < 2; ++ni2) {
      const int n = n0 + (np * 2 + ni2) * 16 + l15;
#pragma unroll
      for (int reg = 0; reg < 4; ++reg)
        C[(size_t)(mbase + reg) * Hh + n] = acc[mi2][ni2][reg];
    }
  }
}

// ---------------------------------------------------------------------------
// group4_acc: S += num/D for 4 h-terms (e = el*er = e^2s, tanh = 1-2/(1+e);
// common denominator over the 4-group). 13 VALU + 1 v_rcp per 4 terms.
// d in [1, ~2e5]; D <= ~2e21 (fp32 safe).
// ---------------------------------------------------------------------------
__device__ __forceinline__ void group4_acc(float& S, const float4 a,
                                           const float4 bv, const float4 u) {
  const float d0 = __builtin_fmaf(a.x, bv.x, 1.0f);
  const float d1 = __builtin_fmaf(a.y, bv.y, 1.0f);
  const float d2 = __builtin_fmaf(a.z, bv.z, 1.0f);
  const float d3 = __builtin_fmaf(a.w, bv.w, 1.0f);
  const float p01 = d0 * d1;
  const float p23 = d2 * d3;
  const float D = p01 * p23;
  float n01 = u.x * d1;
  n01 = __builtin_fmaf(u.y, d0, n01);
  float n23 = u.z * d3;
  n23 = __builtin_fmaf(u.w, d2, n23);
  float num = n01 * p23;
  num = __builtin_fmaf(n23, p01, num);
  S = __builtin_fmaf(num, __builtin_amdgcn_rcpf(D), S);
}

// ---------------------------------------------------------------------------
// combine2: the former gemm epilogue, verbatim — bit-identical el/er values.
// ---------------------------------------------------------------------------
__device__ __forceinline__ float combine2(float a0, float a1) {
  const double s = (double)a0 + (double)a1;
  return __builtin_amdgcn_exp2f((float)(Kc * s));
}

// ---------------------------------------------------------------------------
// Kernel 2a: partial x over a 64-h slice. 64x64 output tile, 4x4 micro-tile,
// split-K=8 (1024 blocks, 34.9 KB LDS -> 4 blocks/CU).
// Staging now reads the TWO gemm K-half partials and applies combine2
// (double add + exp2) — values bit-identical to the old el/er tensors.
// XCD-aware swizzle: XCD k owns batch b=k (elp/erp + part L2-local).
// part[ks][n] = Usl - 2*S  (fp32)
// ---------------------------------------------------------------------------
__global__ __launch_bounds__(256) void biaffine_part(
    const float* __restrict__ elp, const float* __restrict__ erp,
    const float* __restrict__ U, float* __restrict__ part) {
  const int flat = blockIdx.x;      // 0..1023
  const int b = flat & 7;           // batch == XCD
  const int loc = flat >> 3;        // 0..127
  const int ks = loc >> 4;          // 0..7
  const int ib = (loc >> 2) & 3;
  const int jb = loc & 3;
  const int i0 = ib * 64;
  const int j0 = jb * 64;
  const int h0 = ks * 64;

  __shared__ float els[64][68];
  __shared__ float ers[64][68];
  __shared__ float us[64];

  const int t = threadIdx.x;
  if (t < 16) *(float4*)&us[t * 4] = *(const float4*)(U + h0 + t * 4);

  const float* el0 = elp + (size_t)(b * Ll + i0) * Hh + h0;
  const float* er0 = erp + (size_t)(b * Ll + j0) * Hh + h0;
#pragma unroll
  for (int rep = 0; rep < 4; ++rep) {
    const int idx = t + rep * 256;  // 0..1023
    const int r = idx >> 4;         // 0..63
    const int c = (idx & 15) * 4;   // 0..60
    const float4 a0 = *(const float4*)(el0 + (size_t)r * Hh + c);
    const float4 a1 = *(const float4*)(el0 + HALFSZ + (size_t)r * Hh + c);
    els[r][c + 0] = combine2(a0.x, a1.x);
    els[r][c + 1] = combine2(a0.y, a1.y);
    els[r][c + 2] = combine2(a0.z, a1.z);
    els[r][c + 3] = combine2(a0.w, a1.w);
    const float4 b0 = *(const float4*)(er0 + (size_t)r * Hh + c);
    const float4 b1 = *(const float4*)(er0 + HALFSZ + (size_t)r * Hh + c);
    ers[r][c + 0] = combine2(b0.x, b1.x);
    ers[r][c + 1] = combine2(b0.y, b1.y);
    ers[r][c + 2] = combine2(b0.z, b1.z);
    ers[r][c + 3] = combine2(b0.w, b1.w);
  }
  __syncthreads();

  float usl = 0.0f;
#pragma unroll
  for (int q = 0; q < 16; ++q) {
    const float4 u = *(const float4*)&us[q * 4];
    usl += ((u.x + u.y) + u.z) + u.w;
  }

  const int ti = t >> 4;
  const int tj = t & 15;

  float S[4][4];
#pragma unroll
  for (int r = 0; r < 4; ++r)
#pragma unroll
    for (int c = 0; c < 4; ++c) S[r][c] = 0.0f;

  for (int g = 0; g < 16; ++g) {
    const int h = g * 4;
    const float4 u = *(const float4*)&us[h];
    float4 av[4], bv[4];
#pragma unroll
    for (int c = 0; c < 4; ++c) {
      av[c] = *(const float4*)&els[ti + 16 * c][h];
      bv[c] = *(const float4*)&ers[tj + 16 * c][h];
    }
#pragma unroll
    for (int r = 0; r < 4; ++r)
#pragma unroll
      for (int c = 0; c < 4; ++c) group4_acc(S[r][c], av[r], bv[c], u);
  }

  float* pslice = part + (size_t)ks * Nout;
#pragma unroll
  for (int r = 0; r < 4; ++r) {
    const int i = i0 + ti + 16 * r;
#pragma unroll
    for (int c = 0; c < 4; ++c) {
      const int j = j0 + tj + 16 * c;
      const uint32_t n = ((uint32_t)i * Bb + (uint32_t)b) * Ll + (uint32_t)j;
      pslice[n] = __builtin_fmaf(-2.0f, S[r][c], usl);
    }
  }
}

// ---------------------------------------------------------------------------
// Kernel 2b: sum the 8 slice partials (fixed order, fp64), add bias, emit
// samples / mask_scores / entropy. 4 consecutive elements per thread.
// ---------------------------------------------------------------------------
__global__ __launch_bounds__(256) void biaffine_emit(
    const float* __restrict__ part, const float* __restrict__ biasp,
    float* __restrict__ out) {
  const uint32_t n4 = (blockIdx.x * 256u + threadIdx.x) * 4u;
  double s0 = 0.0, s1 = 0.0, s2 = 0.0, s3 = 0.0;
#pragma unroll
  for (int k = 0; k < 8; ++k) {
    const float4 v = *(const float4*)(part + (size_t)k * Nout + n4);
    s0 += (double)v.x;
    s1 += (double)v.y;
    s2 += (double)v.z;
    s3 += (double)v.w;
  }
  const float bias = biasp[0];
  const double sv[4] = {s0, s1, s2, s3};

  float4 samp4, x4, ent4;
  float* sp = &samp4.x;
  float* xp = &x4.x;
  float* ep = &ent4.x;
#pragma unroll
  for (int q = 0; q < 4; ++q) {
    const uint32_t n = n4 + q;
    const int i = (int)(n >> 11);
    const int j = (int)(n & 255u);
    float x = (float)sv[q] + bias;
    if (i == j) x -= 1e8f;  // self-mask

    const double pd = 1.0 / (1.0 + exp(-(double)x));
    const float pf = (float)pd;

    const uint32_t bits = rng_bits(n);
    const float uu = __uint_as_float((bits >> 9) | 0x3f800000u) - 1.0f;
    sp[q] = (uu < pf) ? 1.0f : 0.0f;
    xp[q] = x;

    const float ax = fabsf(x);
    const float l1p = log1pf(expf(-ax));
    const float sp_pos = fmaxf(x, 0.0f) + l1p;
    const float sp_neg = fmaxf(-x, 0.0f) + l1p;
    ep[q] = pf * sp_neg + (1.0f - pf) * sp_pos;
  }
  *(float4*)(out + n4) = samp4;
  *(float4*)(out + Nout + n4) = x4;
  *(float4*)(out + 2 * (size_t)Nout + n4) = ent4;
}

// ---------------------------------------------------------------------------
extern "C" void kernel_launch(void* const* d_in, const int* in_sizes, int n_in,
                              void* d_out, int out_size, void* d_ws,
                              size_t ws_size, hipStream_t stream) {
  const float* enc = (const float*)d_in[0];  // [B,L,D]
  const float* Wl = (const float*)d_in[1];   // [D,H]
  const float* Wr = (const float*)d_in[2];   // [D,H]
  const float* U = (const float*)d_in[3];    // [H]
  const float* lb = (const float*)d_in[4];   // [1]
  float* out = (float*)d_out;

  // workspace layout (bytes)
  char* w = (char*)d_ws;
  float* elp = (float*)w;                     w += 2 * HALFSZ * 4;            // 8 MB
  float* erp = (float*)w;                     w += 2 * HALFSZ * 4;            // 8 MB
  float* part = (float*)w;                    w += (size_t)8 * Nout * 4;      // 16 MB
  unsigned short* ah = (unsigned short*)w;    w += (size_t)Bb * Ll * Dd * 2;  // 2 MB
  unsigned short* am = (unsigned short*)w;    w += (size_t)Bb * Ll * Dd * 2;
  unsigned short* al = (unsigned short*)w;    w += (size_t)Bb * Ll * Dd * 2;
  unsigned short* wh = (unsigned short*)w;    w += (size_t)2 * Dd * Hh * 2;   // 1 MB ea
  unsigned short* wm = (unsigned short*)w;    w += (size_t)2 * Dd * Hh * 2;
  unsigned short* wl = (unsigned short*)w;    w += (size_t)2 * Dd * Hh * 2;

  split_enc<<<dim3((Bb * Ll * Dd) / 1024), 256, 0, stream>>>(enc, ah, am, al);
  split_wt<<<dim3(Dd / 64, Hh / 64, 2), 256, 0, stream>>>(Wl, Wr, wh, wm, wl);
  gemm_mfma<<<dim3(1024, 1, 1), 256, 0, stream>>>(
      ah, am, al, wh, wm, wl, elp, erp);
  biaffine_part<<<dim3(1024, 1, 1), 256, 0, stream>>>(elp, erp, U, part);
  biaffine_emit<<<dim3(Nout / 1024), 256, 0, stream>>>(part, lb, out);
}

// Round 8
// 115.679 us; speedup vs baseline: 1.1084x; 1.1084x over previous
//
#include <hip/hip_runtime.h>
#include <stdint.h>

// Problem constants (B, L, D, H) = (8, 256, 512, 512)
#define Bb 8
#define Ll 256
#define Dd 512
#define Hh 512
#define Nout (Ll * Bb * Ll)  // 524288 elements per output tensor

#define Kc 2.8853900817779268  // 2/ln(2):  exp2(Kc*s) = e^(2s)

// JAX threefry mode: 1 = partitionable (default since jax 0.4.30)
#define RNG_PARTITIONABLE 1

typedef __attribute__((ext_vector_type(8))) short bf16x8;   // 4 VGPRs
typedef __attribute__((ext_vector_type(4))) float f32x4;    // MFMA C/D

// ---------------------------------------------------------------------------
// Fragment-packed plane layout (NEW in R8):
// element (row r, k) lives at  off = mt*8192 + kc*512 + kq*128 + l15*8 + j
//   mt = r>>4, l15 = r&15, kc = k>>5, kq = (k>>3)&3, j = k&7   [u16 units]
// => the 1 KB block for (mt, kc) is CONTIGUOUS and in exactly the per-lane
// order global_load_lds consumes (lane*16B). Staging reads become 8 full
// 128B lines per instruction instead of 16 scattered 64B segments.
// Values are identical to the old planes — pure permutation.
// ---------------------------------------------------------------------------

// ---------------------------------------------------------------------------
// Threefry2x32 with key = (0, 42)  (jax.random.key(42))
// ---------------------------------------------------------------------------
__device__ __forceinline__ uint32_t rotl32(uint32_t v, int s) {
  return (v << s) | (v >> (32 - s));
}
__device__ __forceinline__ void tf_round(uint32_t& x0, uint32_t& x1, int r) {
  x0 += x1;
  x1 = rotl32(x1, r);
  x1 ^= x0;
}
__device__ __forceinline__ uint2 threefry2x32_k042(uint32_t x0, uint32_t x1) {
  const uint32_t k0 = 0u;
  const uint32_t k1 = 42u;
  const uint32_t k2 = 0x1BD11BDAu ^ k0 ^ k1;
  x0 += k0; x1 += k1;
  tf_round(x0, x1, 13); tf_round(x0, x1, 15); tf_round(x0, x1, 26); tf_round(x0, x1, 6);
  x0 += k1; x1 += k2 + 1u;
  tf_round(x0, x1, 17); tf_round(x0, x1, 29); tf_round(x0, x1, 16); tf_round(x0, x1, 24);
  x0 += k2; x1 += k0 + 2u;
  tf_round(x0, x1, 13); tf_round(x0, x1, 15); tf_round(x0, x1, 26); tf_round(x0, x1, 6);
  x0 += k0; x1 += k1 + 3u;
  tf_round(x0, x1, 17); tf_round(x0, x1, 29); tf_round(x0, x1, 16); tf_round(x0, x1, 24);
  x0 += k1; x1 += k2 + 4u;
  tf_round(x0, x1, 13); tf_round(x0, x1, 15); tf_round(x0, x1, 26); tf_round(x0, x1, 6);
  x0 += k2; x1 += k0 + 5u;
  return make_uint2(x0, x1);
}

__device__ __forceinline__ uint32_t rng_bits(uint32_t n) {
#if RNG_PARTITIONABLE
  uint2 o = threefry2x32_k042(0u, n);
  return o.x ^ o.y;
#else
  const uint32_t half = (uint32_t)(Nout / 2);
  if (n < half) {
    uint2 o = threefry2x32_k042(n, n + half);
    return o.x;
  } else {
    uint2 o = threefry2x32_k042(n - half, n);
    return o.y;
  }
#endif
}

// ---------------------------------------------------------------------------
// bf16 helpers (round-to-nearest-even split; residuals are exact in fp32)
// ---------------------------------------------------------------------------
__device__ __forceinline__ unsigned short bf16_rne(float f) {
  uint32_t u = __float_as_uint(f);
  u = (u + 0x7fffu + ((u >> 16) & 1u)) >> 16;
  return (unsigned short)u;
}
__device__ __forceinline__ float bf16_tof(unsigned short h) {
  return __uint_as_float(((uint32_t)h) << 16);
}
__device__ __forceinline__ void split3(float a, unsigned short& h,
                                       unsigned short& m, unsigned short& l) {
  h = bf16_rne(a);
  const float r1 = a - bf16_tof(h);
  m = bf16_rne(r1);
  const float r2 = r1 - bf16_tof(m);
  l = bf16_rne(r2);
}

// fragment-packed offset for (row r, k); valid for A (r = enc row) and
// B (r = Wt row = n), both with 512-deep k. Unit: u16 elements.
__device__ __forceinline__ uint32_t fp_off(int r, int k) {
  const int mt = r >> 4, l15 = r & 15;
  const int kc = k >> 5, kq = (k >> 3) & 3, j = k & 7;
  return (uint32_t)(mt * 8192 + kc * 512 + kq * 128 + l15 * 8 + j);
}

// ---------------------------------------------------------------------------
// Pre-pass 1: split enc (fp32 [2048][512]) into 3 bf16 planes,
// fragment-packed layout. Reads coalesced float4; writes 8B chunks
// (4 consecutive j within one kq block — contiguous & aligned).
// ---------------------------------------------------------------------------
__global__ __launch_bounds__(256) void split_enc(
    const float* __restrict__ enc, unsigned short* __restrict__ ah,
    unsigned short* __restrict__ am, unsigned short* __restrict__ al) {
  const int idx = (blockIdx.x * 256 + threadIdx.x) * 4;
  const int r = idx >> 9;        // row 0..2047
  const int k = idx & 511;       // k, multiple of 4 (j-chunk aligned)
  const float4 v = *(const float4*)(enc + idx);
  ushort4 h4, m4, l4;
  split3(v.x, h4.x, m4.x, l4.x);
  split3(v.y, h4.y, m4.y, l4.y);
  split3(v.z, h4.z, m4.z, l4.z);
  split3(v.w, h4.w, m4.w, l4.w);
  const uint32_t o = fp_off(r, k);
  *(ushort4*)(ah + o) = h4;
  *(ushort4*)(am + o) = m4;
  *(ushort4*)(al + o) = l4;
}

// ---------------------------------------------------------------------------
// Pre-pass 2: Wt[n][k] = W[k][n], split into 3 bf16 planes, fragment-packed.
// 64x64 LDS transpose tile (unchanged); only output addressing changed.
// z = 0 -> W_l, z = 1 -> W_r; outputs offset by z*512*512.
// ---------------------------------------------------------------------------
__global__ __launch_bounds__(256) void split_wt(
    const float* __restrict__ Wl, const float* __restrict__ Wr,
    unsigned short* __restrict__ wh, unsigned short* __restrict__ wm,
    unsigned short* __restrict__ wl) {
  const int z = blockIdx.z;
  const float* W = z ? Wr : Wl;
  const uint32_t zo = (uint32_t)z * Hh * Dd;
  const int k0 = blockIdx.x * 64;
  const int n0 = blockIdx.y * 64;
  __shared__ float tile[64][65];

  const int t = threadIdx.x;
#pragma unroll
  for (int rep = 0; rep < 4; ++rep) {
    const int idx = t + rep * 256;
    const int r = idx >> 4;         // k within tile
    const int c = (idx & 15) * 4;   // n within tile
    const float4 v = *(const float4*)(W + (size_t)(k0 + r) * Hh + n0 + c);
    tile[r][c + 0] = v.x; tile[r][c + 1] = v.y;
    tile[r][c + 2] = v.z; tile[r][c + 3] = v.w;
  }
  __syncthreads();
#pragma unroll
  for (int rep = 0; rep < 4; ++rep) {
    const int idx = t + rep * 256;
    const int rr = idx >> 4;        // n within tile
    const int cc = (idx & 15) * 4;  // k within tile (multiple of 4)
    ushort4 h4, m4, l4;
    split3(tile[cc + 0][rr], h4.x, m4.x, l4.x);
    split3(tile[cc + 1][rr], h4.y, m4.y, l4.y);
    split3(tile[cc + 2][rr], h4.z, m4.z, l4.z);
    split3(tile[cc + 3][rr], h4.w, m4.w, l4.w);
    const uint32_t o = zo + fp_off(n0 + rr, k0 + cc);
    *(ushort4*)(wh + o) = h4;
    *(ushort4*)(wm + o) = m4;
    *(ushort4*)(wl + o) = l4;
  }
}

// ---------------------------------------------------------------------------
// Kernel 1: el/er = exp2(Kc * (enc @ W)) via bf16x3 MFMA (16x16x32),
// LDS-staged with global_load_lds + double buffer — EXACT R1 structure
// (64x64 tile, 512 blocks, XCD swizzle, __syncthreads loop). Only the
// staging SOURCE addresses changed: fragment-packed planes mean each
// global_load_lds reads a CONTIGUOUS 1 KB (8 full 128B lines) instead of
// 16 scattered 64B segments. Values staged are identical -> bit-identical
// el/er (6 MFMAs hh,hm,mh,hl,lh,mm; acc split by K-half; fp64 combine).
// ---------------------------------------------------------------------------
__global__ __launch_bounds__(256) void gemm_mfma(
    const unsigned short* __restrict__ ah, const unsigned short* __restrict__ am,
    const unsigned short* __restrict__ al, const unsigned short* __restrict__ wh,
    const unsigned short* __restrict__ wm, const unsigned short* __restrict__ wl,
    float* __restrict__ el, float* __restrict__ er) {
  const int flat = blockIdx.x;       // 0..511
  const int xcd = flat & 7;
  const int loc = flat >> 3;         // 0..63
  const int z = loc >> 5;            // 0..1
  const int ni = (loc >> 2) & 7;     // 0..7
  const int mi = (xcd << 2) | (loc & 3);  // 0..31
  float* C = z ? er : el;
  const int m0 = mi * 64;
  const int n0 = ni * 64;

  // [buf][12 blocks of 512 u16 = 1KB]
  __shared__ unsigned short Asm[2][12 * 512];
  __shared__ unsigned short Bsm[2][12 * 512];

  const int t = threadIdx.x;
  const int lane = t & 63;
  const int wv = t >> 6;
  const int l15 = lane & 15;

  // staging descriptors: 6 loads per wave, q = wv*6 + s in 0..23.
  // Fragment-packed source: block (tile, kc) at tile*8192 + kc*512, lane*8.
  const unsigned short* gp[6];
  uint32_t go[6];    // element offset, without kc term
  int lq[6];         // LDS block index (u16 units, without buf)
  bool isA[6];
#pragma unroll
  for (int s = 0; s < 6; ++s) {
    const int q = wv * 6 + s;
    if (q < 12) {
      const int p = q >> 2, mt = q & 3;
      gp[s] = (p == 0) ? ah : (p == 1) ? am : al;
      go[s] = (uint32_t)(mi * 4 + mt) * 8192u + (uint32_t)lane * 8u;
      lq[s] = q * 512;
      isA[s] = true;
    } else {
      const int q2 = q - 12;
      const int p = q2 >> 2, nt = q2 & 3;
      gp[s] = (p == 0) ? wh : (p == 1) ? wm : wl;
      go[s] = (uint32_t)z * 262144u + (uint32_t)(ni * 4 + nt) * 8192u +
              (uint32_t)lane * 8u;
      lq[s] = q2 * 512;
      isA[s] = false;
    }
  }

  auto stage = [&](int buf, int kc) {
    const uint32_t k0 = (uint32_t)kc * 512u;
#pragma unroll
    for (int s = 0; s < 6; ++s) {
      unsigned short* dst = isA[s] ? &Asm[buf][lq[s]] : &Bsm[buf][lq[s]];
      __builtin_amdgcn_global_load_lds(
          (const __attribute__((address_space(1))) void*)(gp[s] + go[s] + k0),
          (__attribute__((address_space(3))) void*)dst, 16, 0, 0);
    }
  };

  const int mp = wv & 1;   // m-pair: mtiles {2mp, 2mp+1}
  const int np = wv >> 1;  // n-pair: ntiles {2np, 2np+1}

  f32x4 acc[2][2][2];  // [mi][ni][hf]
#pragma unroll
  for (int mi2 = 0; mi2 < 2; ++mi2)
#pragma unroll
    for (int ni2 = 0; ni2 < 2; ++ni2)
#pragma unroll
      for (int hf = 0; hf < 2; ++hf) acc[mi2][ni2][hf] = (f32x4){0.f, 0.f, 0.f, 0.f};

  stage(0, 0);
  __syncthreads();

  for (int kc = 0; kc < 16; ++kc) {
    const int buf = kc & 1;
    if (kc < 15) stage(buf ^ 1, kc + 1);

    bf16x8 af[2][3], bfr[2][3];
#pragma unroll
    for (int mi2 = 0; mi2 < 2; ++mi2)
#pragma unroll
      for (int p = 0; p < 3; ++p)
        af[mi2][p] = *(const bf16x8*)&Asm[buf][(p * 4 + mp * 2 + mi2) * 512 + lane * 8];
#pragma unroll
    for (int ni2 = 0; ni2 < 2; ++ni2)
#pragma unroll
      for (int p = 0; p < 3; ++p)
        bfr[ni2][p] = *(const bf16x8*)&Bsm[buf][(p * 4 + np * 2 + ni2) * 512 + lane * 8];

    const int hf = kc >> 3;
#pragma unroll
    for (int mi2 = 0; mi2 < 2; ++mi2)
#pragma unroll
      for (int ni2 = 0; ni2 < 2; ++ni2) {
        f32x4 A = acc[mi2][ni2][hf];
        A = __builtin_amdgcn_mfma_f32_16x16x32_bf16(af[mi2][0], bfr[ni2][0], A, 0, 0, 0);
        A = __builtin_amdgcn_mfma_f32_16x16x32_bf16(af[mi2][0], bfr[ni2][1], A, 0, 0, 0);
        A = __builtin_amdgcn_mfma_f32_16x16x32_bf16(af[mi2][1], bfr[ni2][0], A, 0, 0, 0);
        A = __builtin_amdgcn_mfma_f32_16x16x32_bf16(af[mi2][0], bfr[ni2][2], A, 0, 0, 0);
        A = __builtin_amdgcn_mfma_f32_16x16x32_bf16(af[mi2][2], bfr[ni2][0], A, 0, 0, 0);
        A = __builtin_amdgcn_mfma_f32_16x16x32_bf16(af[mi2][1], bfr[ni2][1], A, 0, 0, 0);
        acc[mi2][ni2][hf] = A;
      }
    __syncthreads();
  }

  const int rbase = (lane >> 4) * 4;
#pragma unroll
  for (int mi2 = 0; mi2 < 2; ++mi2) {
    const int mbase = m0 + (mp * 2 + mi2) * 16 + rbase;
#pragma unroll
    for (int ni2 = 0; ni2 < 2; ++ni2) {
      const int n = n0 + (np * 2 + ni2) * 16 + l15;
#pragma unroll
      for (int reg = 0; reg < 4; ++reg) {
        const double s = (double)acc[mi2][ni2][0][reg] + (double)acc[mi2][ni2][1][reg];
        C[(size_t)(mbase + reg) * Hh + n] = __builtin_amdgcn_exp2f((float)(Kc * s));
      }
    }
  }
}

// ---------------------------------------------------------------------------
// group4_acc: S += num/D for 4 h-terms (e = el*er = e^2s, tanh = 1-2/(1+e);
// common denominator over the 4-group). 13 VALU + 1 v_rcp per 4 terms.
// d in [1, ~2e5]; D <= ~2e21 (fp32 safe).
// ---------------------------------------------------------------------------
__device__ __forceinline__ void group4_acc(float& S, const float4 a,
                                           const float4 bv, const float4 u) {
  const float d0 = __builtin_fmaf(a.x, bv.x, 1.0f);
  const float d1 = __builtin_fmaf(a.y, bv.y, 1.0f);
  const float d2 = __builtin_fmaf(a.z, bv.z, 1.0f);
  const float d3 = __builtin_fmaf(a.w, bv.w, 1.0f);
  const float p01 = d0 * d1;
  const float p23 = d2 * d3;
  const float D = p01 * p23;
  float n01 = u.x * d1;
  n01 = __builtin_fmaf(u.y, d0, n01);
  float n23 = u.z * d3;
  n23 = __builtin_fmaf(u.w, d2, n23);
  float num = n01 * p23;
  num = __builtin_fmaf(n23, p01, num);
  S = __builtin_fmaf(num, __builtin_amdgcn_rcpf(D), S);
}

// ---------------------------------------------------------------------------
// Kernel 2a: partial x over a 64-h slice. 64x64 output tile, 4x4 micro-tile,
// split-K=8 (1024 blocks, 34.9 KB LDS -> 4 blocks/CU).
// XCD-aware swizzle: XCD k owns batch b=k. Bijective: flat = b + 8*loc.
// part[ks][n] = Usl - 2*S  (fp32)
// ---------------------------------------------------------------------------
__global__ __launch_bounds__(256) void biaffine_part(
    const float* __restrict__ el, const float* __restrict__ er,
    const float* __restrict__ U, float* __restrict__ part) {
  const int flat = blockIdx.x;      // 0..1023
  const int b = flat & 7;           // batch == XCD
  const int loc = flat >> 3;        // 0..127
  const int ks = loc >> 4;          // 0..7
  const int ib = (loc >> 2) & 3;
  const int jb = loc & 3;
  const int i0 = ib * 64;
  const int j0 = jb * 64;
  const int h0 = ks * 64;

  __shared__ float els[64][68];
  __shared__ float ers[64][68];
  __shared__ float us[64];

  const int t = threadIdx.x;
  if (t < 16) *(float4*)&us[t * 4] = *(const float4*)(U + h0 + t * 4);

  const float* elg = el + (size_t)(b * Ll + i0) * Hh + h0;
  const float* erg = er + (size_t)(b * Ll + j0) * Hh + h0;
#pragma unroll
  for (int rep = 0; rep < 4; ++rep) {
    const int idx = t + rep * 256;  // 0..1023
    const int r = idx >> 4;         // 0..63
    const int c = (idx & 15) * 4;   // 0..60
    *(float4*)&els[r][c] = *(const float4*)(elg + (size_t)r * Hh + c);
    *(float4*)&ers[r][c] = *(const float4*)(erg + (size_t)r * Hh + c);
  }
  __syncthreads();

  float usl = 0.0f;
#pragma unroll
  for (int q = 0; q < 16; ++q) {
    const float4 u = *(const float4*)&us[q * 4];
    usl += ((u.x + u.y) + u.z) + u.w;
  }

  const int ti = t >> 4;
  const int tj = t & 15;

  float S[4][4];
#pragma unroll
  for (int r = 0; r < 4; ++r)
#pragma unroll
    for (int c = 0; c < 4; ++c) S[r][c] = 0.0f;

  for (int g = 0; g < 16; ++g) {
    const int h = g * 4;
    const float4 u = *(const float4*)&us[h];
    float4 av[4], bv[4];
#pragma unroll
    for (int c = 0; c < 4; ++c) {
      av[c] = *(const float4*)&els[ti + 16 * c][h];
      bv[c] = *(const float4*)&ers[tj + 16 * c][h];
    }
#pragma unroll
    for (int r = 0; r < 4; ++r)
#pragma unroll
      for (int c = 0; c < 4; ++c) group4_acc(S[r][c], av[r], bv[c], u);
  }

  float* pslice = part + (size_t)ks * Nout;
#pragma unroll
  for (int r = 0; r < 4; ++r) {
    const int i = i0 + ti + 16 * r;
#pragma unroll
    for (int c = 0; c < 4; ++c) {
      const int j = j0 + tj + 16 * c;
      const uint32_t n = ((uint32_t)i * Bb + (uint32_t)b) * Ll + (uint32_t)j;
      pslice[n] = __builtin_fmaf(-2.0f, S[r][c], usl);
    }
  }
}

// ---------------------------------------------------------------------------
// Kernel 2b: sum the 8 slice partials (fixed order, fp64), add bias, emit
// samples / mask_scores / entropy. 4 consecutive elements per thread.
// ---------------------------------------------------------------------------
__global__ __launch_bounds__(256) void biaffine_emit(
    const float* __restrict__ part, const float* __restrict__ biasp,
    float* __restrict__ out) {
  const uint32_t n4 = (blockIdx.x * 256u + threadIdx.x) * 4u;
  double s0 = 0.0, s1 = 0.0, s2 = 0.0, s3 = 0.0;
#pragma unroll
  for (int k = 0; k < 8; ++k) {
    const float4 v = *(const float4*)(part + (size_t)k * Nout + n4);
    s0 += (double)v.x;
    s1 += (double)v.y;
    s2 += (double)v.z;
    s3 += (double)v.w;
  }
  const float bias = biasp[0];
  const double sv[4] = {s0, s1, s2, s3};

  float4 samp4, x4, ent4;
  float* sp = &samp4.x;
  float* xp = &x4.x;
  float* ep = &ent4.x;
#pragma unroll
  for (int q = 0; q < 4; ++q) {
    const uint32_t n = n4 + q;
    const int i = (int)(n >> 11);
    const int j = (int)(n & 255u);
    float x = (float)sv[q] + bias;
    if (i == j) x -= 1e8f;  // self-mask

    const double pd = 1.0 / (1.0 + exp(-(double)x));
    const float pf = (float)pd;

    const uint32_t bits = rng_bits(n);
    const float uu = __uint_as_float((bits >> 9) | 0x3f800000u) - 1.0f;
    sp[q] = (uu < pf) ? 1.0f : 0.0f;
    xp[q] = x;

    const float ax = fabsf(x);
    const float l1p = log1pf(expf(-ax));
    const float sp_pos = fmaxf(x, 0.0f) + l1p;
    const float sp_neg = fmaxf(-x, 0.0f) + l1p;
    ep[q] = pf * sp_neg + (1.0f - pf) * sp_pos;
  }
  *(float4*)(out + n4) = samp4;
  *(float4*)(out + Nout + n4) = x4;
  *(float4*)(out + 2 * (size_t)Nout + n4) = ent4;
}

// ---------------------------------------------------------------------------
extern "C" void kernel_launch(void* const* d_in, const int* in_sizes, int n_in,
                              void* d_out, int out_size, void* d_ws,
                              size_t ws_size, hipStream_t stream) {
  const float* enc = (const float*)d_in[0];  // [B,L,D]
  const float* Wl = (const float*)d_in[1];   // [D,H]
  const float* Wr = (const float*)d_in[2];   // [D,H]
  const float* U = (const float*)d_in[3];    // [H]
  const float* lb = (const float*)d_in[4];   // [1]
  float* out = (float*)d_out;

  // workspace layout (bytes): fp32 regions first, then u16 planes
  char* w = (char*)d_ws;
  float* el = (float*)w;                      w += (size_t)Bb * Ll * Hh * 4;  // 4 MB
  float* er = (float*)w;                      w += (size_t)Bb * Ll * Hh * 4;  // 4 MB
  float* part = (float*)w;                    w += (size_t)8 * Nout * 4;      // 16 MB
  unsigned short* ah = (unsigned short*)w;    w += (size_t)Bb * Ll * Dd * 2;  // 2 MB
  unsigned short* am = (unsigned short*)w;    w += (size_t)Bb * Ll * Dd * 2;
  unsigned short* al = (unsigned short*)w;    w += (size_t)Bb * Ll * Dd * 2;
  unsigned short* wh = (unsigned short*)w;    w += (size_t)2 * Dd * Hh * 2;   // 1 MB ea
  unsigned short* wm = (unsigned short*)w;    w += (size_t)2 * Dd * Hh * 2;
  unsigned short* wl = (unsigned short*)w;    w += (size_t)2 * Dd * Hh * 2;

  split_enc<<<dim3((Bb * Ll * Dd) / 1024), 256, 0, stream>>>(enc, ah, am, al);
  split_wt<<<dim3(Dd / 64, Hh / 64, 2), 256, 0, stream>>>(Wl, Wr, wh, wm, wl);
  gemm_mfma<<<dim3(512, 1, 1), 256, 0, stream>>>(
      ah, am, al, wh, wm, wl, el, er);
  biaffine_part<<<dim3(1024, 1, 1), 256, 0, stream>>>(el, er, U, part);
  biaffine_emit<<<dim3(Nout / 1024), 256, 0, stream>>>(part, lb, out);
}